// Round 13
// baseline (1546.832 us; speedup 1.0000x reference)
//
#include <hip/hip_runtime.h>
#include <cstddef>

#define T_STEPS 90
#define BT      2048
#define NXV     144
#define HV      128
#define NZV     128
#define M1V     300
#define M2V     200
#define NB      16     // batches per workgroup (1 MFMA N-tile)
#define NTH     512    // 8 waves

typedef __attribute__((ext_vector_type(8))) _Float16 half8v;   // 8 fp16 (4 VGPRs)
typedef __attribute__((ext_vector_type(4))) float f32x4;

// ---- 12 fragment streams (fp16) ----
// g: 0 ENC_IH 1 ENC_HH 2 W1E 3 W2E 4 MU 5 LV 6 DEC_IHX 7 DEC_IHZ 8 DEC_HH 9 W1D 10 W2D 11 WO
constexpr int MTa[12]   = {24,24,19,13, 8, 8,24,24,24,19,13, 9};
constexpr int MREAL[12] = {384,384,300,200,128,128,384,384,384,300,200,144};
constexpr int KREAL[12] = {144,128,128,300,200,200,144,128,128,128,300,200};
constexpr int RSW[12]   = {144,128,128,300,200,200,272,272,128,128,300,200};
constexpr int COW[12]   = {  0,  0,  0,  0,  0,  0,  0,144,  0,  0,  0,  0};
constexpr int P13[13]   = {0,120,240,335,465,521,577,697,817,937,1032,1162,1225};
constexpr int NFRAG = 1225;   // 1225 frags x 1KB = 1.225 MB (L2-resident)

__device__ __forceinline__ float fsig(float v)  { return 1.0f / (1.0f + __expf(-v)); }
__device__ __forceinline__ float ftanh(float v) { return 1.0f - 2.0f / (__expf(2.0f * v) + 1.0f); }

// ---- prep: fp16 MFMA A-fragment streams; bias folded into column k==KREAL ----
__global__ void __launch_bounds__(64)
prep_frags(const float* __restrict__ w_ih_e, const float* __restrict__ w_hh_e,
           const float* __restrict__ W1e,    const float* __restrict__ W2e,
           const float* __restrict__ Wmu,    const float* __restrict__ Wlv,
           const float* __restrict__ w_ih_d, const float* __restrict__ w_hh_d,
           const float* __restrict__ W1d,    const float* __restrict__ W2d,
           const float* __restrict__ Wo,
           const float* __restrict__ b_ih_e, const float* __restrict__ b_hh_e,
           const float* __restrict__ b1e,    const float* __restrict__ b2e,
           const float* __restrict__ bmu,    const float* __restrict__ blv,
           const float* __restrict__ b_ih_d, const float* __restrict__ b_hh_d,
           const float* __restrict__ b1d,    const float* __restrict__ b2d,
           const float* __restrict__ bo,
           _Float16* __restrict__ ws)
{
    int f = blockIdx.x;
    int g = 0;
    while (g < 11 && f >= P13[g + 1]) ++g;
    int fl = f - P13[g];
    int MT = MTa[g];
    int kt = fl / MT, mt = fl - kt * MT;

    const float* W; const float* bias;
    switch (g) {
        case 0:  W = w_ih_e; bias = b_ih_e; break;
        case 1:  W = w_hh_e; bias = b_hh_e; break;
        case 2:  W = W1e;    bias = b1e;    break;
        case 3:  W = W2e;    bias = b2e;    break;
        case 4:  W = Wmu;    bias = bmu;    break;
        case 5:  W = Wlv;    bias = blv;    break;
        case 6:  W = w_ih_d; bias = nullptr; break;
        case 7:  W = w_ih_d; bias = b_ih_d; break;
        case 8:  W = w_hh_d; bias = b_hh_d; break;
        case 9:  W = W1d;    bias = b1d;    break;
        case 10: W = W2d;    bias = b2d;    break;
        default: W = Wo;     bias = bo;     break;
    }
    int l = threadIdx.x;
    int m  = mt * 16 + (l & 15);
    int kb = kt * 32 + (l >> 4) * 8;
    _Float16* dst = ws + (size_t)f * 512 + (size_t)l * 8;
    #pragma unroll
    for (int j = 0; j < 8; ++j) {
        int k = kb + j;
        float val = 0.0f;
        if (m < MREAL[g]) {
            if (k < KREAL[g]) val = W[(size_t)m * RSW[g] + COW[g] + k];
            else if (k == KREAL[g] && bias) val = bias[m];
        }
        dst[j] = (_Float16)val;
    }
}

// ---- gate GEMM from REGISTER-resident fragments (15 frags = tiles {w,w+8,w+16} x 5 kt)
template<int RS>
__device__ __forceinline__ void gate_gemm_reg(const half8v (&gw)[15],
                                              const _Float16* __restrict__ Bt,
                                              int l, f32x4 (&acc)[3])
{
    const int bo_ = (l & 15) * RS + ((l >> 4) << 3);
    #pragma unroll
    for (int kt = 0; kt < 5; ++kt) {
        half8v bf = *(const half8v*)(Bt + bo_ + kt * 32);
        #pragma unroll
        for (int j = 0; j < 3; ++j)
            acc[j] = __builtin_amdgcn_mfma_f32_16x16x32_f16(gw[kt * 3 + j], bf, acc[j], 0, 0, 0);
    }
}

// ---- streamed GEMM: prefetch A-frags to registers, then MFMA. Wave w owns
// M-tiles w+8*i. KOFF: starting k-tile offset of this A-stream within B.
template<int MT, int KT, int NT, int RS, int KOFF = 0>
__device__ __forceinline__ void mlp_stream(const half8v* __restrict__ A,
                                           const _Float16* __restrict__ Bt,
                                           int w, int l, f32x4 (&acc)[NT])
{
    half8v af[NT * KT];
    #pragma unroll
    for (int i = 0; i < NT; ++i) {
        int mt = w + 8 * i;
        if (mt < MT) {
            #pragma unroll
            for (int kt = 0; kt < KT; ++kt)
                af[i * KT + kt] = A[(size_t)(kt * MT + mt) * 64 + l];
        }
    }
    const int bo_ = (l & 15) * RS + ((l >> 4) << 3);
    #pragma unroll
    for (int kt = 0; kt < KT; ++kt) {
        half8v bf = *(const half8v*)(Bt + bo_ + (KOFF + kt) * 32);
        #pragma unroll
        for (int i = 0; i < NT; ++i) {
            int mt = w + 8 * i;
            if (mt < MT)
                acc[i] = __builtin_amdgcn_mfma_f32_16x16x32_f16(af[i * KT + kt], bf, acc[i], 0, 0, 0);
        }
    }
}

// tanh epilogue -> fp16 act buffer (single N-tile); masks padded m (protects bias col)
template<int MT, int NT, int RS>
__device__ __forceinline__ void write_tanhN(const f32x4 (&acc)[NT], int Mreal,
                                            _Float16* __restrict__ T, int w, int l)
{
    int b = l & 15, q4 = (l >> 4) << 2;
    #pragma unroll
    for (int i = 0; i < NT; ++i) {
        int mt = w + 8 * i;
        if (mt < MT) {
            #pragma unroll
            for (int r = 0; r < 4; ++r) {
                int m = mt * 16 + q4 + r;
                if (m < Mreal) T[b * RS + m] = (_Float16)ftanh(acc[i][r]);
            }
        }
    }
}

__global__ void __launch_bounds__(NTH, 2)
vae_mfma(const float* __restrict__ x, const half8v* __restrict__ wsv,
         float* __restrict__ out)
{
    // act buffers [b][k] fp16 (k-pad zero, bias col = 1). W2d now streams from L2.
    __shared__ __align__(16) _Float16 xT [NB * 168];
    __shared__ __align__(16) _Float16 hT [NB * 168];
    __shared__ __align__(16) _Float16 m1T[NB * 328];   // doubles as zT (RS=328)
    __shared__ __align__(16) _Float16 m2T[NB * 232];

    const int tid = threadIdx.x;
    const int w = tid >> 6, l = tid & 63;
    const int bbase = blockIdx.x * NB;
    const size_t XREC_SZ = (size_t)T_STEPS * BT * NXV;
    const size_t MU_OFF = XREC_SZ;
    const size_t LV_OFF = XREC_SZ + (size_t)BT * NZV;
    const f32x4 z4 = {0.f, 0.f, 0.f, 0.f};

#define AHI(g) (wsv + (size_t)P13[g] * 64)

    auto load_x = [&](int t, float xr[5]) {
        #pragma unroll
        for (int u = 0; u < 5; ++u) {
            int i = u * NTH + tid;
            if (i < NB * NXV)
                xr[u] = __builtin_nontemporal_load(
                    &x[(size_t)t * (BT * NXV) + (size_t)(bbase + i / NXV) * NXV + (i % NXV)]);
        }
    };
    auto store_x = [&](const float xr[5]) {
        #pragma unroll
        for (int u = 0; u < 5; ++u) {
            int i = u * NTH + tid;
            if (i < NB * NXV) {
                int b2 = i / NXV, k = i - b2 * NXV;
                xT[b2 * 168 + k] = (_Float16)xr[u];
            }
        }
    };

    // register-resident gate fragments (reloaded for decoder)
    half8v gih[15], ghh[15];
    auto load_gates = [&](const half8v* Gih, const half8v* Ghh) {
        #pragma unroll
        for (int kt = 0; kt < 5; ++kt) {
            #pragma unroll
            for (int j = 0; j < 3; ++j) {
                gih[kt * 3 + j] = Gih[(size_t)(kt * 24 + w + 8 * j) * 64 + l];
                ghh[kt * 3 + j] = Ghh[(size_t)(kt * 24 + w + 8 * j) * 64 + l];
            }
        }
    };

    // per-wave hidden state: unit j = 16*w + (l>>4)*4 + r, batch l&15
    float hreg[4] = {0.f, 0.f, 0.f, 0.f};
    auto gru_combine = [&](const f32x4 (&ai)[3], const f32x4 (&ah)[3]) {
        #pragma unroll
        for (int r = 0; r < 4; ++r) {
            float rr = fsig(ai[0][r] + ah[0][r]);
            float zz = fsig(ai[1][r] + ah[1][r]);
            float nn = ftanh(ai[2][r] + rr * ah[2][r]);
            hreg[r] = (1.f - zz) * nn + zz * hreg[r];
        }
    };
    auto write_h = [&]() {
        int jb = 16 * w + ((l >> 4) << 2), b = l & 15;
        #pragma unroll
        for (int r = 0; r < 4; ++r) hT[b * 168 + jb + r] = (_Float16)hreg[r];
    };

    // ---- init: zero act buffers; load encoder gate frags ----
    for (int i = tid; i < NB * 168; i += NTH) { xT[i] = (_Float16)0.f; hT[i] = (_Float16)0.f; }
    for (int i = tid; i < NB * 328; i += NTH) m1T[i] = (_Float16)0.f;
    for (int i = tid; i < NB * 232; i += NTH) m2T[i] = (_Float16)0.f;
    load_gates(AHI(0), AHI(1));
    float xr[5] = {0, 0, 0, 0, 0};
    load_x(0, xr);
    __syncthreads();
    if (tid < NB) {   // bias-1 columns (persist; rewrites skip these)
        xT [tid * 168 + 144] = (_Float16)1.f;
        hT [tid * 168 + 128] = (_Float16)1.f;
        m1T[tid * 328 + 300] = (_Float16)1.f;
        m2T[tid * 232 + 200] = (_Float16)1.f;
    }
    store_x(xr);
    load_x(1, xr);
    __syncthreads();

    // ================= encoder GRU: 90 steps (zero global loads in gates) =====
    for (int t = 0; t < T_STEPS; ++t) {
        f32x4 ai[3] = {z4, z4, z4}, ah[3] = {z4, z4, z4};
        gate_gemm_reg<168>(gih, xT, l, ai);
        gate_gemm_reg<168>(ghh, hT, l, ah);
        gru_combine(ai, ah);
        __syncthreads();              // all reads of xT/hT done
        write_h();
        if (t + 1 < T_STEPS) {
            store_x(xr);
            if (t + 2 < T_STEPS) load_x(t + 2, xr);
        }
        __syncthreads();
    }

    // ================= encoder MLP + latent heads =================
    {
        f32x4 a1[3] = {z4, z4, z4};
        mlp_stream<19, 5, 3, 168>(AHI(2), hT, w, l, a1);
        write_tanhN<19, 3, 328>(a1, M1V, m1T, w, l);
        __syncthreads();
        f32x4 a2[2] = {z4, z4};
        mlp_stream<13, 10, 2, 328>(AHI(3), m1T, w, l, a2);
        write_tanhN<13, 2, 232>(a2, M2V, m2T, w, l);
        __syncthreads();
        f32x4 am[1] = {z4}, av[1] = {z4};
        mlp_stream<8, 7, 1, 232>(AHI(4), m2T, w, l, am);   // mu (tile w)
        mlp_stream<8, 7, 1, 232>(AHI(5), m2T, w, l, av);   // logvar
        __syncthreads();   // m1T reads (g3) done -> safe to overwrite with z
        int b = l & 15, q4 = (l >> 4) << 2;
        int m = w * 16 + q4;
        __builtin_nontemporal_store(am[0], (f32x4*)&out[MU_OFF + (size_t)(bbase + b) * NZV + m]);
        __builtin_nontemporal_store(av[0], (f32x4*)&out[LV_OFF + (size_t)(bbase + b) * NZV + m]);
        #pragma unroll
        for (int r = 0; r < 4; ++r)            // z = mu -> m1T-as-zT (RS=328)
            m1T[b * 328 + m + r] = (_Float16)am[0][r];
    }

    // ================= decoder init =================
    f32x4 gzr[3] = {z4, z4, z4};   // b_ih_d + W_ihd[:,144:272] @ z (time-invariant)
    {
        for (int i = tid; i < NB * HV; i += NTH) {     // h0 = 0 (keep bias col)
            int b2 = i >> 7, j = i & 127;
            hT[b2 * 168 + j] = (_Float16)0.f;
        }
        if (tid < NB) m1T[tid * 328 + 128] = (_Float16)1.f;   // z bias col
        float xr0[5] = {0, 0, 0, 0, 0};
        load_x(0, xr0);
        store_x(xr0);                                  // xp = x[0]
        __syncthreads();                               // z + bias visible
        mlp_stream<24, 5, 3, 328>(AHI(7), m1T, w, l, gzr);
        load_gates(AHI(6), AHI(8));                    // decoder gate frags -> regs
        #pragma unroll
        for (int r = 0; r < 4; ++r) hreg[r] = 0.f;
    }
    __syncthreads();

    // ================= decoder: 90 autoregressive steps =================
    for (int t = 0; t < T_STEPS; ++t) {
        f32x4 ai[3], ah[3];
        #pragma unroll
        for (int i = 0; i < 3; ++i) { ai[i] = gzr[i]; ah[i] = z4; }
        gate_gemm_reg<168>(gih, xT, l, ai);
        gate_gemm_reg<168>(ghh, hT, l, ah);
        gru_combine(ai, ah);
        __syncthreads();          // gate reads of xT/hT done
        write_h();
        __syncthreads();
        f32x4 a1[3] = {z4, z4, z4};
        mlp_stream<19, 5, 3, 168>(AHI(9), hT, w, l, a1);   // W1d: L2 stream
        write_tanhN<19, 3, 328>(a1, M1V, m1T, w, l);
        __syncthreads();
        // issue Wo loads NOW (consumed after next barrier -> latency hidden
        // under the W2d streamed GEMM)
        half8v wo_af[14];
        #pragma unroll
        for (int kt = 0; kt < 7; ++kt) {
            #pragma unroll
            for (int i = 0; i < 2; ++i)
                if (w + 8 * i < 9)
                    wo_af[kt * 2 + i] = AHI(11)[(size_t)(kt * 9 + w + 8 * i) * 64 + l];
        }
        // W2d: two streamed half-passes from L2 (was LDS-resident; frees the
        // LDS pipe ~160 ops/CU/step -> VMEM pipe which is idle)
        f32x4 a2[2] = {z4, z4};
        mlp_stream<13, 5, 2, 328, 0>(AHI(10), m1T, w, l, a2);
        mlp_stream<13, 5, 2, 328, 5>(AHI(10) + (size_t)(5 * 13) * 64, m1T, w, l, a2);
        write_tanhN<13, 2, 232>(a2, M2V, m2T, w, l);
        __syncthreads();
        f32x4 ao[2] = {z4, z4};
        gemm_regwo: ;
        {
            const int bo_ = (l & 15) * 232 + ((l >> 4) << 3);
            #pragma unroll
            for (int kt = 0; kt < 7; ++kt) {
                half8v bf = *(const half8v*)(m2T + bo_ + kt * 32);
                #pragma unroll
                for (int i = 0; i < 2; ++i)
                    if (w + 8 * i < 9)
                        ao[i] = __builtin_amdgcn_mfma_f32_16x16x32_f16(wo_af[kt * 2 + i], bf, ao[i], 0, 0, 0);
            }
        }
        {   // epilogue: nt global store (16B) + fp16 feedback into xT
            int b = l & 15, q4 = (l >> 4) << 2;
            #pragma unroll
            for (int i2 = 0; i2 < 2; ++i2) {
                int mt = w + 8 * i2;
                if (mt < 9) {
                    int m = mt * 16 + q4;
                    __builtin_nontemporal_store(ao[i2],
                        (f32x4*)&out[(size_t)t * (BT * NXV) + (size_t)(bbase + b) * NXV + m]);
                    #pragma unroll
                    for (int r = 0; r < 4; ++r)
                        xT[b * 168 + m + r] = (_Float16)ao[i2][r];
                }
            }
        }
        __syncthreads();
    }
#undef AHI
}

extern "C" void kernel_launch(void* const* d_in, const int* in_sizes, int n_in,
                              void* d_out, int out_size, void* d_ws, size_t ws_size,
                              hipStream_t stream) {
    (void)in_sizes; (void)n_in; (void)out_size; (void)ws_size;
    const float* p[23];
    for (int i = 0; i < 23; ++i) p[i] = (const float*)d_in[i];
    _Float16* ws = (_Float16*)d_ws;   // 1225 KB

    prep_frags<<<dim3(NFRAG), dim3(64), 0, stream>>>(
        p[1], p[2], p[5], p[7], p[9], p[11], p[13], p[14], p[17], p[19], p[21],
        p[3], p[4], p[6], p[8], p[10], p[12], p[15], p[16], p[18], p[20], p[22],
        ws);

    vae_mfma<<<dim3(BT / NB), dim3(NTH), 0, stream>>>(
        p[0], (const half8v*)ws, (float*)d_out);
}

// Round 14
// 994.018 us; speedup vs baseline: 1.5561x; 1.5561x over previous
//
#include <hip/hip_runtime.h>
#include <cstddef>

#define T_STEPS 90
#define BT      2048
#define NXV     144
#define HV      128
#define NZV     128
#define M1V     300
#define M2V     200
#define NB      16     // batches per workgroup (1 MFMA N-tile)
#define NTH     1024   // 16 waves (4/SIMD)

typedef __attribute__((ext_vector_type(8))) _Float16 half8v;   // 8 fp16 (4 VGPRs)
typedef __attribute__((ext_vector_type(4))) float f32x4;

// ---- 12 fragment streams (fp16; bias folded into column k==KREAL) ----
// g: 0 ENC_IH 1 ENC_HH 2 W1E 3 W2E 4 MU 5 LV 6 DEC_IHX 7 DEC_IHZ 8 DEC_HH 9 W1D 10 W2D 11 WO
constexpr int MTa[12]   = {24,24,19,13, 8, 8,24,24,24,19,13, 9};
constexpr int MREAL[12] = {384,384,300,200,128,128,384,384,384,300,200,144};
constexpr int KREAL[12] = {144,128,128,300,200,200,144,128,128,128,300,200};
constexpr int RSW[12]   = {144,128,128,300,200,200,272,272,128,128,300,200};
constexpr int COW[12]   = {  0,  0,  0,  0,  0,  0,  0,144,  0,  0,  0,  0};
constexpr int P13[13]   = {0,120,240,335,465,521,577,697,817,937,1032,1162,1225};
constexpr int NFRAG = 1225;   // 1.225 MB (L2-resident)

__device__ __forceinline__ float fsig(float v)  { return 1.0f / (1.0f + __expf(-v)); }
__device__ __forceinline__ float ftanh(float v) { return 1.0f - 2.0f / (__expf(2.0f * v) + 1.0f); }

__global__ void __launch_bounds__(64)
prep_frags(const float* __restrict__ w_ih_e, const float* __restrict__ w_hh_e,
           const float* __restrict__ W1e,    const float* __restrict__ W2e,
           const float* __restrict__ Wmu,    const float* __restrict__ Wlv,
           const float* __restrict__ w_ih_d, const float* __restrict__ w_hh_d,
           const float* __restrict__ W1d,    const float* __restrict__ W2d,
           const float* __restrict__ Wo,
           const float* __restrict__ b_ih_e, const float* __restrict__ b_hh_e,
           const float* __restrict__ b1e,    const float* __restrict__ b2e,
           const float* __restrict__ bmu,    const float* __restrict__ blv,
           const float* __restrict__ b_ih_d, const float* __restrict__ b_hh_d,
           const float* __restrict__ b1d,    const float* __restrict__ b2d,
           const float* __restrict__ bo,
           _Float16* __restrict__ ws)
{
    int f = blockIdx.x;
    int g = 0;
    while (g < 11 && f >= P13[g + 1]) ++g;
    int fl = f - P13[g];
    int MT = MTa[g];
    int kt = fl / MT, mt = fl - kt * MT;

    const float* W; const float* bias;
    switch (g) {
        case 0:  W = w_ih_e; bias = b_ih_e; break;
        case 1:  W = w_hh_e; bias = b_hh_e; break;
        case 2:  W = W1e;    bias = b1e;    break;
        case 3:  W = W2e;    bias = b2e;    break;
        case 4:  W = Wmu;    bias = bmu;    break;
        case 5:  W = Wlv;    bias = blv;    break;
        case 6:  W = w_ih_d; bias = nullptr; break;
        case 7:  W = w_ih_d; bias = b_ih_d; break;
        case 8:  W = w_hh_d; bias = b_hh_d; break;
        case 9:  W = W1d;    bias = b1d;    break;
        case 10: W = W2d;    bias = b2d;    break;
        default: W = Wo;     bias = bo;     break;
    }
    int l = threadIdx.x;
    int m  = mt * 16 + (l & 15);
    int kb = kt * 32 + (l >> 4) * 8;
    _Float16* dst = ws + (size_t)f * 512 + (size_t)l * 8;
    #pragma unroll
    for (int j = 0; j < 8; ++j) {
        int k = kb + j;
        float val = 0.0f;
        if (m < MREAL[g]) {
            if (k < KREAL[g]) val = W[(size_t)m * RSW[g] + COW[g] + k];
            else if (k == KREAL[g] && bias) val = bias[m];
        }
        dst[j] = (_Float16)val;
    }
}

// NT=1 streamed GEMM helpers (single M-tile per call; af reused sequentially)
template<int MT, int KT>
__device__ __forceinline__ void sload1(const half8v* __restrict__ A, int mt, int l,
                                       half8v (&af)[KT]) {
    if (mt < MT) {
        #pragma unroll
        for (int kt = 0; kt < KT; ++kt)
            af[kt] = A[(size_t)(kt * MT + mt) * 64 + l];
    }
}
template<int MT, int KT, int RS>
__device__ __forceinline__ void smfma1(const half8v (&af)[KT],
                                       const _Float16* __restrict__ Bt,
                                       int mt, int l, f32x4& acc) {
    if (mt < MT) {
        const int bo_ = (l & 15) * RS + ((l >> 4) << 3);
        #pragma unroll
        for (int kt = 0; kt < KT; ++kt) {
            half8v bf = *(const half8v*)(Bt + bo_ + kt * 32);
            acc = __builtin_amdgcn_mfma_f32_16x16x32_f16(af[kt], bf, acc, 0, 0, 0);
        }
    }
}
// tanh epilogue, single tile
template<int RS>
__device__ __forceinline__ void writeT1(const f32x4& a, int mt, int Mreal,
                                        _Float16* __restrict__ T, int l) {
    int b = l & 15, q4 = (l >> 4) << 2;
    #pragma unroll
    for (int r = 0; r < 4; ++r) {
        int m = mt * 16 + q4 + r;
        if (m < Mreal) T[b * RS + m] = (_Float16)ftanh(a[r]);
    }
}

__global__ void __launch_bounds__(NTH, 4)
vae_mfma(const float* __restrict__ x, const half8v* __restrict__ wsv,
         float* __restrict__ out)
{
    // act buffers [b][k] fp16 (k-pad zero, bias col = 1)
    __shared__ __align__(16) _Float16 xT [NB * 168];
    __shared__ __align__(16) _Float16 hT [NB * 168];
    __shared__ __align__(16) _Float16 m1T[NB * 328];   // doubles as zT
    __shared__ __align__(16) _Float16 m2T[NB * 232];
    __shared__ __align__(16) float    pbuf[8 * 3 * 256];  // ah partials (24 KB)
    __shared__ __align__(16) _Float16 g10L[104 * 512];    // W2d kt 0..7 (104 KB)

    const int tid = threadIdx.x;
    const int w = tid >> 6, l = tid & 63;
    const int v = w & 7;               // gate tile index within half
    const bool LO = (w < 8);           // LO: ih-gates + combine; HI: hh-gates
    const int bbase = blockIdx.x * NB;
    const size_t XREC_SZ = (size_t)T_STEPS * BT * NXV;
    const size_t MU_OFF = XREC_SZ;
    const size_t LV_OFF = XREC_SZ + (size_t)BT * NZV;
    const f32x4 z4 = {0.f, 0.f, 0.f, 0.f};

#define AHI(g) (wsv + (size_t)P13[g] * 64)

    // x staging on waves 8..15 only (512 threads, 2304 elems -> 5 loads each)
    auto load_x = [&](int t, float xr[5]) {
        int tid2 = tid - 512;
        #pragma unroll
        for (int u = 0; u < 5; ++u) {
            int i = u * 512 + tid2;
            if (i < NB * NXV)
                xr[u] = __builtin_nontemporal_load(
                    &x[(size_t)t * (BT * NXV) + (size_t)(bbase + i / NXV) * NXV + (i % NXV)]);
        }
    };
    auto store_x = [&](const float xr[5]) {
        int tid2 = tid - 512;
        #pragma unroll
        for (int u = 0; u < 5; ++u) {
            int i = u * 512 + tid2;
            if (i < NB * NXV) {
                int b2 = i / NXV, k = i - b2 * NXV;
                xT[b2 * 168 + k] = (_Float16)xr[u];
            }
        }
    };

    // gate frags: LO waves hold ih, HI waves hold hh (SAME variable -> union = 60 VGPR)
    half8v gfr[15];
    auto load_gates = [&](const half8v* G) {
        #pragma unroll
        for (int kt = 0; kt < 5; ++kt)
            #pragma unroll
            for (int j = 0; j < 3; ++j)
                gfr[kt * 3 + j] = G[(size_t)(kt * 24 + v + 8 * j) * 64 + l];
    };
    auto ggemm = [&](const _Float16* __restrict__ Bt, f32x4 (&acc)[3]) {
        const int bo_ = (l & 15) * 168 + ((l >> 4) << 3);
        #pragma unroll
        for (int kt = 0; kt < 5; ++kt) {
            half8v bf = *(const half8v*)(Bt + bo_ + kt * 32);
            #pragma unroll
            for (int j = 0; j < 3; ++j)
                acc[j] = __builtin_amdgcn_mfma_f32_16x16x32_f16(gfr[kt * 3 + j], bf, acc[j], 0, 0, 0);
        }
    };

    float hreg[4] = {0.f, 0.f, 0.f, 0.f};   // LO waves: unit j = 16*v + (l>>4)*4 + r
    auto combine_write = [&](const f32x4 (&ai)[3]) {   // LO only; reads HI partials
        f32x4 p0 = *(const f32x4*)&pbuf[((v * 3 + 0) * 64 + l) * 4];
        f32x4 p1 = *(const f32x4*)&pbuf[((v * 3 + 1) * 64 + l) * 4];
        f32x4 p2 = *(const f32x4*)&pbuf[((v * 3 + 2) * 64 + l) * 4];
        int jb = 16 * v + ((l >> 4) << 2), b = l & 15;
        #pragma unroll
        for (int r = 0; r < 4; ++r) {
            float rr = fsig(ai[0][r] + p0[r]);
            float zz = fsig(ai[1][r] + p1[r]);
            float nn = ftanh(ai[2][r] + rr * p2[r]);
            hreg[r] = (1.f - zz) * nn + zz * hreg[r];
            hT[b * 168 + jb + r] = (_Float16)hreg[r];
        }
    };

    // ---- init ----
    for (int i = tid; i < NB * 168; i += NTH) { xT[i] = (_Float16)0.f; hT[i] = (_Float16)0.f; }
    for (int i = tid; i < NB * 328; i += NTH) m1T[i] = (_Float16)0.f;
    for (int i = tid; i < NB * 232; i += NTH) m2T[i] = (_Float16)0.f;
    for (int i = tid; i < 104 * 64; i += NTH)
        *(half8v*)(g10L + (size_t)i * 8) = AHI(10)[i];
    load_gates(LO ? AHI(0) : AHI(1));
    float xr[5] = {0, 0, 0, 0, 0};
    if (!LO) load_x(0, xr);
    __syncthreads();
    if (tid < NB) {   // bias-1 columns (persist; rewrites skip these)
        xT [tid * 168 + 144] = (_Float16)1.f;
        hT [tid * 168 + 128] = (_Float16)1.f;
        m1T[tid * 328 + 300] = (_Float16)1.f;
        m2T[tid * 232 + 200] = (_Float16)1.f;
    }
    if (!LO) { store_x(xr); load_x(1, xr); }
    __syncthreads();

    // ================= encoder GRU: 90 steps, 2 barriers each =================
    for (int t = 0; t < T_STEPS; ++t) {
        f32x4 acc[3] = {z4, z4, z4};
        if (LO) {
            ggemm(xT, acc);                          // ai
        } else {
            ggemm(hT, acc);                          // ah -> partials
            #pragma unroll
            for (int j = 0; j < 3; ++j)
                *(f32x4*)&pbuf[((v * 3 + j) * 64 + l) * 4] = acc[j];
        }
        __syncthreads();                             // B1
        if (LO) {
            combine_write(acc);
        } else if (t + 1 < T_STEPS) {
            store_x(xr);
            if (t + 2 < T_STEPS) load_x(t + 2, xr);
        }
        __syncthreads();                             // B2
    }

    // ================= encoder MLP + latent heads (M-split over 16 waves) =====
    {
        half8v af5[5];
        f32x4 a1 = z4;
        sload1<19, 5>(AHI(2), w, l, af5);
        smfma1<19, 5, 168>(af5, hT, w, l, a1);
        writeT1<328>(a1, w, M1V, m1T, l);
        if (w + 16 < 19) {
            sload1<19, 5>(AHI(2), w + 16, l, af5);
            f32x4 a1b = z4;
            smfma1<19, 5, 168>(af5, hT, w + 16, l, a1b);
            writeT1<328>(a1b, w + 16, M1V, m1T, l);
        }
        __syncthreads();
        if (w < 13) {
            half8v af10[10];
            sload1<13, 10>(AHI(3), w, l, af10);
            f32x4 a2 = z4;
            smfma1<13, 10, 328>(af10, m1T, w, l, a2);
            writeT1<232>(a2, w, M2V, m2T, l);
        }
        __syncthreads();
        // heads in parallel: LO -> mu tile v, HI -> logvar tile v
        half8v af7[7];
        f32x4 ahd = z4;
        sload1<8, 7>(LO ? AHI(4) : AHI(5), v, l, af7);
        smfma1<8, 7, 232>(af7, m2T, v, l, ahd);
        int b = l & 15, q4 = (l >> 4) << 2;
        int m = v * 16 + q4;
        if (LO) {
            __builtin_nontemporal_store(ahd, (f32x4*)&out[MU_OFF + (size_t)(bbase + b) * NZV + m]);
            #pragma unroll
            for (int r = 0; r < 4; ++r)        // z = mu -> m1T-as-zT
                m1T[b * 328 + m + r] = (_Float16)ahd[r];
        } else {
            __builtin_nontemporal_store(ahd, (f32x4*)&out[LV_OFF + (size_t)(bbase + b) * NZV + m]);
        }
    }
    __syncthreads();

    // ================= decoder init =================
    f32x4 gzr[3] = {z4, z4, z4};
    {
        for (int i = tid; i < NB * HV; i += NTH) {     // h0 = 0 (keep bias col 128)
            int b2 = i >> 7, j = i & 127;
            hT[b2 * 168 + j] = (_Float16)0.f;
        }
        if (tid < NB) m1T[tid * 328 + 128] = (_Float16)1.f;   // z bias col
        if (!LO) {
            float xr0[5] = {0, 0, 0, 0, 0};
            load_x(0, xr0);
            store_x(xr0);                               // xp = x[0]
        }
        __syncthreads();                                // z + bias + h0 + x0 visible
        if (LO) {   // gzr = b_ih_d + Wz @ z, tiles {v, v+8, v+16}, sequential (low reg)
            half8v afz[5];
            #pragma unroll
            for (int j = 0; j < 3; ++j) {
                sload1<24, 5>(AHI(7), v + 8 * j, l, afz);
                f32x4 g = z4;
                smfma1<24, 5, 328>(afz, m1T, v + 8 * j, l, g);
                gzr[j] = g;
            }
            #pragma unroll
            for (int r = 0; r < 4; ++r) hreg[r] = 0.f;
        }
        load_gates(LO ? AHI(6) : AHI(8));               // decoder gate frags
    }
    __syncthreads();

    // ================= decoder: 90 steps, 5 barriers each =================
    for (int t = 0; t < T_STEPS; ++t) {
        f32x4 acc[3];
        half8v afw1[5];                       // W1d tile-w frags (HI: early-issued)
        if (LO) {
            #pragma unroll
            for (int i = 0; i < 3; ++i) acc[i] = gzr[i];
            ggemm(xT, acc);                   // ai = gzr + ih @ xp
        } else {
            #pragma unroll
            for (int i = 0; i < 3; ++i) acc[i] = z4;
            ggemm(hT, acc);                   // ah
            #pragma unroll
            for (int j = 0; j < 3; ++j)
                *(f32x4*)&pbuf[((v * 3 + j) * 64 + l) * 4] = acc[j];
            sload1<19, 5>(AHI(9), w, l, afw1);   // early-issue W1d loads (L2 latency hidden)
        }
        __syncthreads();                      // B1: partials visible
        if (LO) combine_write(acc);
        __syncthreads();                      // B2: h_new visible
        // P3: W1d, tile w (all 16 waves) + tiles 16..18 second pass (waves 0-2)
        if (LO) sload1<19, 5>(AHI(9), w, l, afw1);
        {
            f32x4 a1 = z4;
            smfma1<19, 5, 168>(afw1, hT, w, l, a1);
            writeT1<328>(a1, w, M1V, m1T, l);
            if (w < 3) {
                half8v afb[5];
                sload1<19, 5>(AHI(9), 16 + w, l, afb);
                f32x4 a1b = z4;
                smfma1<19, 5, 168>(afb, hT, 16 + w, l, a1b);
                writeT1<328>(a1b, 16 + w, M1V, m1T, l);
            }
        }
        __syncthreads();                      // B3: m1 visible
        // P4: W2d tile w (waves 0-12): kt0..7 from LDS, kt8,9 streamed (issued first)
        if (w < 13) {
            half8v af2a = AHI(10)[(size_t)(8 * 13 + w) * 64 + l];
            half8v af2b = AHI(10)[(size_t)(9 * 13 + w) * 64 + l];
            f32x4 a2 = z4;
            const int bo2 = (l & 15) * 328 + ((l >> 4) << 3);
            #pragma unroll
            for (int kt = 0; kt < 8; ++kt) {
                half8v bf = *(const half8v*)(m1T + bo2 + kt * 32);
                half8v afL = *(const half8v*)(g10L + ((size_t)(kt * 13 + w) * 64 + l) * 8);
                a2 = __builtin_amdgcn_mfma_f32_16x16x32_f16(afL, bf, a2, 0, 0, 0);
            }
            {
                half8v bf8 = *(const half8v*)(m1T + bo2 + 8 * 32);
                half8v bf9 = *(const half8v*)(m1T + bo2 + 9 * 32);
                a2 = __builtin_amdgcn_mfma_f32_16x16x32_f16(af2a, bf8, a2, 0, 0, 0);
                a2 = __builtin_amdgcn_mfma_f32_16x16x32_f16(af2b, bf9, a2, 0, 0, 0);
            }
            writeT1<232>(a2, w, M2V, m2T, l);
        }
        __syncthreads();                      // B4: m2 visible
        // P5: Wo tile w (waves 0-8) + epilogue
        if (w < 9) {
            half8v afo[7];
            sload1<9, 7>(AHI(11), w, l, afo);
            f32x4 ao = z4;
            smfma1<9, 7, 232>(afo, m2T, w, l, ao);
            int b = l & 15, q4 = (l >> 4) << 2;
            int m = w * 16 + q4;
            __builtin_nontemporal_store(ao,
                (f32x4*)&out[(size_t)t * (BT * NXV) + (size_t)(bbase + b) * NXV + m]);
            #pragma unroll
            for (int r = 0; r < 4; ++r)
                xT[b * 168 + m + r] = (_Float16)ao[r];   // autoregressive feedback
        }
        __syncthreads();                      // B5: x_new visible
    }
#undef AHI
}

extern "C" void kernel_launch(void* const* d_in, const int* in_sizes, int n_in,
                              void* d_out, int out_size, void* d_ws, size_t ws_size,
                              hipStream_t stream) {
    (void)in_sizes; (void)n_in; (void)out_size; (void)ws_size;
    const float* p[23];
    for (int i = 0; i < 23; ++i) p[i] = (const float*)d_in[i];
    _Float16* ws = (_Float16*)d_ws;   // 1225 KB

    prep_frags<<<dim3(NFRAG), dim3(64), 0, stream>>>(
        p[1], p[2], p[5], p[7], p[9], p[11], p[13], p[14], p[17], p[19], p[21],
        p[3], p[4], p[6], p[8], p[10], p[12], p[15], p[16], p[18], p[20], p[22],
        ws);

    vae_mfma<<<dim3(BT / NB), dim3(NTH), 0, stream>>>(
        p[0], (const half8v*)ws, (float*)d_out);
}

// Round 15
// 864.691 us; speedup vs baseline: 1.7889x; 1.1496x over previous
//
#include <hip/hip_runtime.h>
#include <cstddef>

#define T_STEPS 90
#define BT      2048
#define NXV     144
#define HV      128
#define NZV     128
#define M1V     300
#define M2V     200
#define NB      16     // batches per workgroup (1 MFMA N-tile)
#define NTH     512    // 8 waves

typedef __attribute__((ext_vector_type(8))) _Float16 half8v;   // 8 fp16 (4 VGPRs)
typedef __attribute__((ext_vector_type(4))) float f32x4;

// ---- 12 fragment streams (fp16) ----
// g: 0 ENC_IH 1 ENC_HH 2 W1E 3 W2E 4 MU 5 LV 6 DEC_IHX 7 DEC_IHZ 8 DEC_HH 9 W1D 10 W2D 11 WO
constexpr int MTa[12]   = {24,24,19,13, 8, 8,24,24,24,19,13, 9};
constexpr int MREAL[12] = {384,384,300,200,128,128,384,384,384,300,200,144};
constexpr int KREAL[12] = {144,128,128,300,200,200,144,128,128,128,300,200};
constexpr int RSW[12]   = {144,128,128,300,200,200,272,272,128,128,300,200};
constexpr int COW[12]   = {  0,  0,  0,  0,  0,  0,  0,144,  0,  0,  0,  0};
constexpr int P13[13]   = {0,120,240,335,465,521,577,697,817,937,1032,1162,1225};
constexpr int NFRAG = 1225;   // 1225 frags x 1KB = 1.225 MB (L2-resident)

__device__ __forceinline__ float fsig(float v)  { return 1.0f / (1.0f + __expf(-v)); }
__device__ __forceinline__ float ftanh(float v) { return 1.0f - 2.0f / (__expf(2.0f * v) + 1.0f); }

// ---- prep: fp16 MFMA A-fragment streams; bias folded into column k==KREAL ----
__global__ void __launch_bounds__(64)
prep_frags(const float* __restrict__ w_ih_e, const float* __restrict__ w_hh_e,
           const float* __restrict__ W1e,    const float* __restrict__ W2e,
           const float* __restrict__ Wmu,    const float* __restrict__ Wlv,
           const float* __restrict__ w_ih_d, const float* __restrict__ w_hh_d,
           const float* __restrict__ W1d,    const float* __restrict__ W2d,
           const float* __restrict__ Wo,
           const float* __restrict__ b_ih_e, const float* __restrict__ b_hh_e,
           const float* __restrict__ b1e,    const float* __restrict__ b2e,
           const float* __restrict__ bmu,    const float* __restrict__ blv,
           const float* __restrict__ b_ih_d, const float* __restrict__ b_hh_d,
           const float* __restrict__ b1d,    const float* __restrict__ b2d,
           const float* __restrict__ bo,
           _Float16* __restrict__ ws)
{
    int f = blockIdx.x;
    int g = 0;
    while (g < 11 && f >= P13[g + 1]) ++g;
    int fl = f - P13[g];
    int MT = MTa[g];
    int kt = fl / MT, mt = fl - kt * MT;

    const float* W; const float* bias;
    switch (g) {
        case 0:  W = w_ih_e; bias = b_ih_e; break;
        case 1:  W = w_hh_e; bias = b_hh_e; break;
        case 2:  W = W1e;    bias = b1e;    break;
        case 3:  W = W2e;    bias = b2e;    break;
        case 4:  W = Wmu;    bias = bmu;    break;
        case 5:  W = Wlv;    bias = blv;    break;
        case 6:  W = w_ih_d; bias = nullptr; break;
        case 7:  W = w_ih_d; bias = b_ih_d; break;
        case 8:  W = w_hh_d; bias = b_hh_d; break;
        case 9:  W = W1d;    bias = b1d;    break;
        case 10: W = W2d;    bias = b2d;    break;
        default: W = Wo;     bias = bo;     break;
    }
    int l = threadIdx.x;
    int m  = mt * 16 + (l & 15);
    int kb = kt * 32 + (l >> 4) * 8;
    _Float16* dst = ws + (size_t)f * 512 + (size_t)l * 8;
    #pragma unroll
    for (int j = 0; j < 8; ++j) {
        int k = kb + j;
        float val = 0.0f;
        if (m < MREAL[g]) {
            if (k < KREAL[g]) val = W[(size_t)m * RSW[g] + COW[g] + k];
            else if (k == KREAL[g] && bias) val = bias[m];
        }
        dst[j] = (_Float16)val;
    }
}

// ---- gate GEMM from REGISTER-resident fragments (15 frags = tiles {w,w+8,w+16} x 5 kt)
template<int RS>
__device__ __forceinline__ void gate_gemm_reg(const half8v (&gw)[15],
                                              const _Float16* __restrict__ Bt,
                                              int l, f32x4 (&acc)[3])
{
    const int bo_ = (l & 15) * RS + ((l >> 4) << 3);
    #pragma unroll
    for (int kt = 0; kt < 5; ++kt) {
        half8v bf = *(const half8v*)(Bt + bo_ + kt * 32);
        #pragma unroll
        for (int j = 0; j < 3; ++j)
            acc[j] = __builtin_amdgcn_mfma_f32_16x16x32_f16(gw[kt * 3 + j], bf, acc[j], 0, 0, 0);
    }
}

// ---- streamed GEMM: prefetch ALL A-frags to registers, then MFMA. Wave w owns
// M-tiles w+8*i.
template<int MT, int KT, int NT, int RS>
__device__ __forceinline__ void mlp_stream(const half8v* __restrict__ A,
                                           const _Float16* __restrict__ Bt,
                                           int w, int l, f32x4 (&acc)[NT])
{
    half8v af[NT * KT];
    #pragma unroll
    for (int i = 0; i < NT; ++i) {
        int mt = w + 8 * i;
        if (mt < MT) {
            #pragma unroll
            for (int kt = 0; kt < KT; ++kt)
                af[i * KT + kt] = A[(size_t)(kt * MT + mt) * 64 + l];
        }
    }
    const int bo_ = (l & 15) * RS + ((l >> 4) << 3);
    #pragma unroll
    for (int kt = 0; kt < KT; ++kt) {
        half8v bf = *(const half8v*)(Bt + bo_ + kt * 32);
        #pragma unroll
        for (int i = 0; i < NT; ++i) {
            int mt = w + 8 * i;
            if (mt < MT)
                acc[i] = __builtin_amdgcn_mfma_f32_16x16x32_f16(af[i * KT + kt], bf, acc[i], 0, 0, 0);
        }
    }
}

// ---- GEMM with A staged in LDS (conflict-free: lane stride 16B) ----
template<int MT, int KT, int NT, int RS>
__device__ __forceinline__ void mlp_lds(const _Float16* __restrict__ Alds,
                                        const _Float16* __restrict__ Bt,
                                        int w, int l, f32x4 (&acc)[NT])
{
    const int bo_ = (l & 15) * RS + ((l >> 4) << 3);
    #pragma unroll
    for (int kt = 0; kt < KT; ++kt) {
        half8v bf = *(const half8v*)(Bt + bo_ + kt * 32);
        #pragma unroll
        for (int i = 0; i < NT; ++i) {
            int mt = w + 8 * i;
            if (mt < MT) {
                half8v af = *(const half8v*)(Alds + ((size_t)(kt * MT + mt) * 64 + l) * 8);
                acc[i] = __builtin_amdgcn_mfma_f32_16x16x32_f16(af, bf, acc[i], 0, 0, 0);
            }
        }
    }
}

// tanh epilogue -> fp16 act buffer (single N-tile); masks padded m (protects bias col)
template<int MT, int NT, int RS>
__device__ __forceinline__ void write_tanhN(const f32x4 (&acc)[NT], int Mreal,
                                            _Float16* __restrict__ T, int w, int l)
{
    int b = l & 15, q4 = (l >> 4) << 2;
    #pragma unroll
    for (int i = 0; i < NT; ++i) {
        int mt = w + 8 * i;
        if (mt < MT) {
            #pragma unroll
            for (int r = 0; r < 4; ++r) {
                int m = mt * 16 + q4 + r;
                if (m < Mreal) T[b * RS + m] = (_Float16)ftanh(acc[i][r]);
            }
        }
    }
}

__global__ void __launch_bounds__(NTH, 2)
vae_mfma(const float* __restrict__ x, const half8v* __restrict__ wsv,
         float* __restrict__ out)
{
    // act buffers [b][k] fp16 (k-pad zero, bias col = 1); W2d staged in LDS.
    __shared__ __align__(16) _Float16 xT [NB * 168];
    __shared__ __align__(16) _Float16 hT [NB * 168];
    __shared__ __align__(16) _Float16 m1T[NB * 328];   // doubles as zT (RS=328)
    __shared__ __align__(16) _Float16 m2T[NB * 232];
    __shared__ __align__(16) _Float16 g10L[130 * 512]; // W2d frags (130 KB)

    const int tid = threadIdx.x;
    const int w = tid >> 6, l = tid & 63;
    const int bbase = blockIdx.x * NB;
    const size_t XREC_SZ = (size_t)T_STEPS * BT * NXV;
    const size_t MU_OFF = XREC_SZ;
    const size_t LV_OFF = XREC_SZ + (size_t)BT * NZV;
    const f32x4 z4 = {0.f, 0.f, 0.f, 0.f};

#define AHI(g) (wsv + (size_t)P13[g] * 64)

    auto load_x = [&](int t, float xr[5]) {
        #pragma unroll
        for (int u = 0; u < 5; ++u) {
            int i = u * NTH + tid;
            if (i < NB * NXV)
                xr[u] = __builtin_nontemporal_load(
                    &x[(size_t)t * (BT * NXV) + (size_t)(bbase + i / NXV) * NXV + (i % NXV)]);
        }
    };
    auto store_x = [&](const float xr[5]) {
        #pragma unroll
        for (int u = 0; u < 5; ++u) {
            int i = u * NTH + tid;
            if (i < NB * NXV) {
                int b2 = i / NXV, k = i - b2 * NXV;
                xT[b2 * 168 + k] = (_Float16)xr[u];
            }
        }
    };

    // register-resident gate fragments (reloaded for decoder)
    half8v gih[15], ghh[15];
    auto load_gates = [&](const half8v* Gih, const half8v* Ghh) {
        #pragma unroll
        for (int kt = 0; kt < 5; ++kt) {
            #pragma unroll
            for (int j = 0; j < 3; ++j) {
                gih[kt * 3 + j] = Gih[(size_t)(kt * 24 + w + 8 * j) * 64 + l];
                ghh[kt * 3 + j] = Ghh[(size_t)(kt * 24 + w + 8 * j) * 64 + l];
            }
        }
    };

    // per-wave hidden state: unit j = 16*w + (l>>4)*4 + r, batch l&15
    float hreg[4] = {0.f, 0.f, 0.f, 0.f};
    auto gru_combine = [&](const f32x4 (&ai)[3], const f32x4 (&ah)[3]) {
        #pragma unroll
        for (int r = 0; r < 4; ++r) {
            float rr = fsig(ai[0][r] + ah[0][r]);
            float zz = fsig(ai[1][r] + ah[1][r]);
            float nn = ftanh(ai[2][r] + rr * ah[2][r]);
            hreg[r] = (1.f - zz) * nn + zz * hreg[r];
        }
    };
    auto write_h = [&]() {
        int jb = 16 * w + ((l >> 4) << 2), b = l & 15;
        #pragma unroll
        for (int r = 0; r < 4; ++r) hT[b * 168 + jb + r] = (_Float16)hreg[r];
    };

    // ---- init: zero act buffers; stage W2d into LDS; load encoder gate frags ----
    for (int i = tid; i < NB * 168; i += NTH) { xT[i] = (_Float16)0.f; hT[i] = (_Float16)0.f; }
    for (int i = tid; i < NB * 328; i += NTH) m1T[i] = (_Float16)0.f;
    for (int i = tid; i < NB * 232; i += NTH) m2T[i] = (_Float16)0.f;
    for (int i = tid; i < 130 * 64; i += NTH)
        *(half8v*)(g10L + (size_t)i * 8) = AHI(10)[i];
    load_gates(AHI(0), AHI(1));
    float xrA[5] = {0, 0, 0, 0, 0}, xrB[5] = {0, 0, 0, 0, 0};
    load_x(0, xrA);
    __syncthreads();
    if (tid < NB) {   // bias-1 columns (persist; rewrites skip these)
        xT [tid * 168 + 144] = (_Float16)1.f;
        hT [tid * 168 + 128] = (_Float16)1.f;
        m1T[tid * 328 + 300] = (_Float16)1.f;
        m2T[tid * 232 + 200] = (_Float16)1.f;
    }
    store_x(xrA);
    load_x(1, xrA);
    __syncthreads();

    // ================= encoder GRU: 90 steps (2-step pairs, early x-issue) =====
    // invariant at top of even step t: xT = x_t, xrA = x_{t+1}
    for (int t = 0; t < T_STEPS; t += 2) {
        {   // even step t: load x_{t+2} -> xrB EARLY (hidden under gates)
            if (t + 2 < T_STEPS) load_x(t + 2, xrB);
            f32x4 ai[3] = {z4, z4, z4}, ah[3] = {z4, z4, z4};
            gate_gemm_reg<168>(gih, xT, l, ai);
            gate_gemm_reg<168>(ghh, hT, l, ah);
            gru_combine(ai, ah);
            __syncthreads();              // all reads of xT/hT done
            write_h();
            if (t + 1 < T_STEPS) store_x(xrA);
            __syncthreads();
        }
        {   // odd step t+1: load x_{t+3} -> xrA EARLY
            if (t + 3 < T_STEPS) load_x(t + 3, xrA);
            f32x4 ai[3] = {z4, z4, z4}, ah[3] = {z4, z4, z4};
            gate_gemm_reg<168>(gih, xT, l, ai);
            gate_gemm_reg<168>(ghh, hT, l, ah);
            gru_combine(ai, ah);
            __syncthreads();
            write_h();
            if (t + 2 < T_STEPS) store_x(xrB);
            __syncthreads();
        }
    }

    // ================= encoder MLP + latent heads =================
    {
        f32x4 a1[3] = {z4, z4, z4};
        mlp_stream<19, 5, 3, 168>(AHI(2), hT, w, l, a1);
        write_tanhN<19, 3, 328>(a1, M1V, m1T, w, l);
        __syncthreads();
        f32x4 a2[2] = {z4, z4};
        mlp_stream<13, 10, 2, 328>(AHI(3), m1T, w, l, a2);
        write_tanhN<13, 2, 232>(a2, M2V, m2T, w, l);
        __syncthreads();
        f32x4 am[1] = {z4}, av[1] = {z4};
        mlp_stream<8, 7, 1, 232>(AHI(4), m2T, w, l, am);   // mu (tile w)
        mlp_stream<8, 7, 1, 232>(AHI(5), m2T, w, l, av);   // logvar
        __syncthreads();   // m1T reads (g3) done -> safe to overwrite with z
        int b = l & 15, q4 = (l >> 4) << 2;
        int m = w * 16 + q4;
        __builtin_nontemporal_store(am[0], (f32x4*)&out[MU_OFF + (size_t)(bbase + b) * NZV + m]);
        __builtin_nontemporal_store(av[0], (f32x4*)&out[LV_OFF + (size_t)(bbase + b) * NZV + m]);
        #pragma unroll
        for (int r = 0; r < 4; ++r)            // z = mu -> m1T-as-zT (RS=328)
            m1T[b * 328 + m + r] = (_Float16)am[0][r];
    }

    // ================= decoder init =================
    f32x4 gzr[3] = {z4, z4, z4};   // b_ih_d + W_ihd[:,144:272] @ z (time-invariant)
    {
        for (int i = tid; i < NB * HV; i += NTH) {     // h0 = 0 (keep bias col)
            int b2 = i >> 7, j = i & 127;
            hT[b2 * 168 + j] = (_Float16)0.f;
        }
        if (tid < NB) m1T[tid * 328 + 128] = (_Float16)1.f;   // z bias col
        float xr0[5] = {0, 0, 0, 0, 0};
        load_x(0, xr0);
        store_x(xr0);                                  // xp = x[0]
        __syncthreads();                               // z + bias visible
        mlp_stream<24, 5, 3, 328>(AHI(7), m1T, w, l, gzr);
        load_gates(AHI(6), AHI(8));                    // decoder gate frags -> regs
        #pragma unroll
        for (int r = 0; r < 4; ++r) hreg[r] = 0.f;
    }
    __syncthreads();

    // ================= decoder: 90 autoregressive steps =================
    // out-store DEFERRED one iteration: ao(t-1) stored at head of step t, so the
    // HBM store-ack drains during the gate phase instead of stalling B5.
    f32x4 aop[2] = {z4, z4};
    for (int t = 0; t < T_STEPS; ++t) {
        if (t > 0 && w < 9) {   // store step t-1's output rows
            int b = l & 15, q4 = (l >> 4) << 2;
            #pragma unroll
            for (int i2 = 0; i2 < 2; ++i2) {
                int mt = w + 8 * i2;
                if (mt < 9)
                    __builtin_nontemporal_store(aop[i2],
                        (f32x4*)&out[(size_t)(t - 1) * (BT * NXV) + (size_t)(bbase + b) * NXV + mt * 16 + q4]);
            }
        }
        f32x4 ai[3], ah[3];
        #pragma unroll
        for (int i = 0; i < 3; ++i) { ai[i] = gzr[i]; ah[i] = z4; }
        gate_gemm_reg<168>(gih, xT, l, ai);
        gate_gemm_reg<168>(ghh, hT, l, ah);
        gru_combine(ai, ah);
        __syncthreads();          // gate reads of xT/hT done
        write_h();
        __syncthreads();
        f32x4 a1[3] = {z4, z4, z4};
        mlp_stream<19, 5, 3, 168>(AHI(9), hT, w, l, a1);   // W1d: L2 stream
        write_tanhN<19, 3, 328>(a1, M1V, m1T, w, l);
        __syncthreads();
        f32x4 a2[2] = {z4, z4};
        mlp_lds<13, 10, 2, 328>(g10L, m1T, w, l, a2);      // W2d: LDS-resident
        write_tanhN<13, 2, 232>(a2, M2V, m2T, w, l);
        __syncthreads();
        f32x4 ao[2] = {z4, z4};
        mlp_stream<9, 7, 2, 232>(AHI(11), m2T, w, l, ao);  // Wo: L2 stream
        {   // epilogue: fp16 feedback into xT now; global store deferred
            int b = l & 15, q4 = (l >> 4) << 2;
            #pragma unroll
            for (int i2 = 0; i2 < 2; ++i2) {
                int mt = w + 8 * i2;
                if (mt < 9) {
                    int m = mt * 16 + q4;
                    #pragma unroll
                    for (int r = 0; r < 4; ++r)
                        xT[b * 168 + m + r] = (_Float16)ao[i2][r];
                    aop[i2] = ao[i2];
                }
            }
        }
        __syncthreads();
    }
    if (w < 9) {   // final step's deferred store
        int b = l & 15, q4 = (l >> 4) << 2;
        #pragma unroll
        for (int i2 = 0; i2 < 2; ++i2) {
            int mt = w + 8 * i2;
            if (mt < 9)
                __builtin_nontemporal_store(aop[i2],
                    (f32x4*)&out[(size_t)(T_STEPS - 1) * (BT * NXV) + (size_t)(bbase + b) * NXV + mt * 16 + q4]);
        }
    }
#undef AHI
}

extern "C" void kernel_launch(void* const* d_in, const int* in_sizes, int n_in,
                              void* d_out, int out_size, void* d_ws, size_t ws_size,
                              hipStream_t stream) {
    (void)in_sizes; (void)n_in; (void)out_size; (void)ws_size;
    const float* p[23];
    for (int i = 0; i < 23; ++i) p[i] = (const float*)d_in[i];
    _Float16* ws = (_Float16*)d_ws;   // 1225 KB

    prep_frags<<<dim3(NFRAG), dim3(64), 0, stream>>>(
        p[1], p[2], p[5], p[7], p[9], p[11], p[13], p[14], p[17], p[19], p[21],
        p[3], p[4], p[6], p[8], p[10], p[12], p[15], p[16], p[18], p[20], p[22],
        ws);

    vae_mfma<<<dim3(BT / NB), dim3(NTH), 0, stream>>>(
        p[0], (const half8v*)ws, (float*)d_out);
}